// Round 13
// baseline (341.023 us; speedup 1.0000x reference)
//
#include <hip/hip_runtime.h>
#include <hip/hip_bf16.h>
#include <stdint.h>

typedef short bhalf8 __attribute__((ext_vector_type(8)));
typedef float facc4 __attribute__((ext_vector_type(4)));

static __device__ __forceinline__ unsigned short f2bfu(float f) {
  return __builtin_bit_cast(unsigned short, __float2bfloat16(f));
}

// ---------------------------------------------------------------------------
// prep: sample conv weights w = loc + L@eps (L = tril(-1)+softplus(diag)*I)
// bf16 layout wt[a=kh*3+kw][kc=i>>5][o][i&31], bias, 16-short zero pad.
// ---------------------------------------------------------------------------
__global__ void prep_kernel(const float* __restrict__ wloc,
                            const float* __restrict__ wL,
                            const float* __restrict__ eps_w,
                            const float* __restrict__ bloc,
                            const float* __restrict__ bro,
                            const float* __restrict__ eps_b,
                            short* __restrict__ wt, float* __restrict__ bias,
                            short* __restrict__ zeros) {
  int t = blockIdx.x * 256 + threadIdx.x;  // t = o*64 + i
  int o = t >> 6, i = t & 63;
  int kc = i >> 5, il = i & 31;
  const float* Lp = wL + (size_t)t * 81;
  const float* ep = eps_w + (size_t)t * 9;
  const float* lp = wloc + (size_t)t * 9;
  float e[9];
#pragma unroll
  for (int b = 0; b < 9; ++b) e[b] = ep[b];
#pragma unroll
  for (int a = 0; a < 9; ++a) {
    float s = lp[a];
    for (int b = 0; b < a; ++b) s += Lp[a * 9 + b] * e[b];
    float d = Lp[a * 9 + a];
    float sp = (d > 20.f) ? d : log1pf(expf(d));
    s += sp * e[a];
    wt[((a * 2 + kc) * 64 + o) * 32 + il] = (short)f2bfu(s);
  }
  if (t < 64) {
    float d = bro[t];
    float sp = (d > 20.f) ? d : log1pf(expf(d));
    bias[t] = bloc[t] + eps_b[t] * sp;
  }
  if (t < 16) zeros[t] = 0;
}

// ---------------------------------------------------------------------------
// pass 1: x NCHW f32 -> NHWC bf16 ([n][p=h*224+w][c64]). Streaming ~5.4 TB/s.
// ---------------------------------------------------------------------------
__global__ __launch_bounds__(512) void to_nhwc_kernel(
    const float* __restrict__ x, short* __restrict__ xh) {
  int b = blockIdx.x;
  int n = b / 196;
  int p0 = (b % 196) * 256;
  int t = threadIdx.x;
  int pl = t >> 3, c8 = t & 7;
  const float* xp = x + (size_t)(n * 64 + c8 * 8) * 50176 + p0 + pl * 4;
  short* op = xh + ((size_t)n * 50176 + p0 + pl * 4) * 64 + c8 * 8;
  float4 v[8];
#pragma unroll
  for (int j = 0; j < 8; ++j) v[j] = *(const float4*)(xp + (size_t)j * 50176);
#pragma unroll
  for (int s = 0; s < 4; ++s) {
    bhalf8 h;
#pragma unroll
    for (int j = 0; j < 8; ++j) h[j] = f2bfu(((const float*)&v[j])[s]);
    *(bhalf8*)(op + s * 64) = h;
  }
}

// ---------------------------------------------------------------------------
// pass 2: wc-loop pipelined conv. Block = 8 waves, 64o x 8r x 32px, sweeps a
// HALF-ROW (4 or 3 wc tiles) x 2 ic = 8/6 rounds -> prologue amortized 4x.
// LDS: x dbuf 2 x [10r][4g][34cc][8ch] (21.76 KB each) + wt single
// [9a][4g][64o][8ch] (36.9 KB) = 80.4 KB -> 2 blocks/CU. Palindromic ic
// order (0,1|1,0|0,1|..) halves wt restages; restage issued right after the
// reads-done barrier (L2 latency hides under next stage-issue). Per-wave
// UNIFORM issue counts (x:3, wt:5) make vmcnt(3) exact: at each wait,
// outstanding = next-x only. Grid 1792 = 32n x 28ht x 2half, XCD-chunked,
// consecutive blocks share rows (L2 halo reuse).
// ---------------------------------------------------------------------------
#define XBUF 10880  // shorts per x buffer (1360 chunks * 8)

__global__ __launch_bounds__(512, 4) void conv_wcloop_kernel(
    const short* __restrict__ xh, const short* __restrict__ wtg,
    const float* __restrict__ bias, const short* __restrict__ zeros,
    float* __restrict__ out) {
  extern __shared__ short smem[];
  short* lds_x = smem;          // 2 * 10880 shorts = 43520 B
  short* lds_w = smem + 21760;  // 2304 chunks * 8 = 18432 shorts = 36864 B

  int b0 = blockIdx.x;
  int b = (b0 & 7) * 224 + (b0 >> 3);  // bijective: 1792 % 8 == 0
  int half = b & 1;
  int b2 = b >> 1;
  int ht = b2 % 28, n = b2 / 28;
  int h0 = ht * 8;
  const int wc0 = half ? 4 : 0;
  const int nr = half ? 6 : 8;  // (3 or 4 wc tiles) * 2 ic
  int t = threadIdx.x, lane = t & 63, wv = t >> 6;
  int l15 = lane & 15, l4 = lane >> 4;
  const size_t nbase = (size_t)n * 50176 * 64;

  // ---- per-k stage geometry (wave slice = 170 chunks, uniform 3 issues) ----
  // chunk id = (r*4+g)*34 + cc ; id = wv*170 + k*64 + lane
  int pre_hrow[3], pre_cc[3], pre_g8[3];
#pragma unroll
  for (int k = 0; k < 3; ++k) {
    int id = wv * 170 + k * 64 + lane;
    if (id >= 1360) id = 0;  // masked lanes: unused
    int cc = id % 34;
    int rg = id / 34;
    int g = rg & 3, r = rg >> 2;
    int h_in = h0 - 1 + r;
    pre_hrow[k] = (h_in >= 0 && h_in < 224) ? h_in * 14336 : -1;  // *224*64
    pre_cc[k] = cc;
    pre_g8[k] = g * 8;
  }

#define STAGE_X(bufsel, wc_, ic_)                                          \
  do {                                                                     \
    const int w0_ = (wc0 + (wc_)) * 32;                                    \
    short* lx_ = lds_x + (bufsel)*XBUF + wv * 1360;                        \
    _Pragma("unroll") for (int k = 0; k < 3; ++k) {                        \
      if (k * 64 + lane < 170) {                                           \
        int w_in = w0_ - 1 + pre_cc[k];                                    \
        bool ok = (pre_hrow[k] >= 0) & (w_in >= 0) & (w_in < 224);         \
        const short* src = ok ? xh + nbase + pre_hrow[k] + w_in * 64 +     \
                                    pre_g8[k] + (ic_)*32                   \
                              : zeros;                                     \
        __builtin_amdgcn_global_load_lds(                                  \
            (const __attribute__((address_space(1))) void*)src,            \
            (__attribute__((address_space(3))) void*)(lx_ + k * 512), 16,  \
            0, 0);                                                         \
      }                                                                    \
    }                                                                      \
  } while (0)

  // wt: 2304 chunks; wave slice = 288 (uniform 5 issues, k=4 half-masked)
#define STAGE_W(ic_)                                                       \
  do {                                                                     \
    short* lw_ = lds_w + wv * 2304;                                        \
    _Pragma("unroll") for (int k = 0; k < 5; ++k) {                        \
      if (k * 64 + lane < 288) {                                           \
        int wid = wv * 288 + k * 64 + lane;                                \
        int a_ = wid >> 8, rem_ = wid & 255;                               \
        int g_ = rem_ >> 6, o_ = rem_ & 63;                                \
        const short* src =                                                 \
            wtg + ((a_ * 2 + (ic_)) * 64 + o_) * 32 + g_ * 8;              \
        __builtin_amdgcn_global_load_lds(                                  \
            (const __attribute__((address_space(1))) void*)src,            \
            (__attribute__((address_space(3))) void*)(lw_ + k * 512), 16,  \
            0, 0);                                                         \
      }                                                                    \
    }                                                                      \
  } while (0)

  facc4 acc[4][2];
#pragma unroll
  for (int om = 0; om < 4; ++om)
#pragma unroll
    for (int p = 0; p < 2; ++p) {
      facc4 z = {0.f, 0.f, 0.f, 0.f};
      acc[om][p] = z;
    }

  // ---- prologue ----
  STAGE_X(0, 0, 0);
  STAGE_W(0);
  asm volatile("s_waitcnt vmcnt(0)" ::: "memory");
  __builtin_amdgcn_sched_barrier(0);
  __builtin_amdgcn_s_barrier();
  __builtin_amdgcn_sched_barrier(0);

  // ---- rounds: ic palindrome 0,1,1,0,0,1,(1,0) ----
  for (int rr = 0; rr < nr; ++rr) {
    const int ic = ((rr + 1) >> 1) & 1;
    const int icn = ((rr + 2) >> 1) & 1;
    if (rr + 1 < nr) STAGE_X((rr + 1) & 1, (rr + 1) >> 1, icn);
    __builtin_amdgcn_sched_barrier(0);
    if (rr + 1 < nr)
      asm volatile("s_waitcnt vmcnt(3)" ::: "memory");
    else
      asm volatile("s_waitcnt vmcnt(0)" ::: "memory");
    __builtin_amdgcn_sched_barrier(0);
    __builtin_amdgcn_s_barrier();  // round data ready
    __builtin_amdgcn_sched_barrier(0);

    const short* bx = lds_x + (rr & 1) * XBUF;
    __builtin_amdgcn_s_setprio(1);
#pragma unroll
    for (int kh = 0; kh < 3; ++kh) {
      int r = wv + kh;
#pragma unroll
      for (int kw = 0; kw < 3; ++kw) {
        const int a_ = kh * 3 + kw;
        bhalf8 av[4];
#pragma unroll
        for (int om = 0; om < 4; ++om)
          av[om] =
              *(const bhalf8*)(lds_w + ((a_ * 4 + l4) * 64 + om * 16 + l15) * 8);
#pragma unroll
        for (int p = 0; p < 2; ++p) {
          int tc = p * 16 + l15 + kw;
          bhalf8 bv = *(const bhalf8*)(bx + ((r * 4 + l4) * 34 + tc) * 8);
#pragma unroll
          for (int om = 0; om < 4; ++om)
            acc[om][p] = __builtin_amdgcn_mfma_f32_16x16x32_bf16(
                av[om], bv, acc[om][p], 0, 0, 0);
        }
      }
    }
    __builtin_amdgcn_s_setprio(0);

    if (rr & 1) {
      // second ic of this wc tile done -> write out, reset acc
      const int w0_ = (wc0 + (rr >> 1)) * 32;
      int h = h0 + wv;
#pragma unroll
      for (int om = 0; om < 4; ++om) {
#pragma unroll
        for (int jj = 0; jj < 4; ++jj) {
          int o = om * 16 + l4 * 4 + jj;
          float bo = bias[o];
          float* op = out + ((size_t)(n * 64 + o) * 224 + h) * 224 + w0_;
#pragma unroll
          for (int p = 0; p < 2; ++p) op[p * 16 + l15] = acc[om][p][jj] + bo;
        }
      }
#pragma unroll
      for (int om = 0; om < 4; ++om)
#pragma unroll
        for (int p = 0; p < 2; ++p) {
          facc4 z = {0.f, 0.f, 0.f, 0.f};
          acc[om][p] = z;
        }
    }
    __builtin_amdgcn_s_barrier();  // all reads of x-buf + wt done
    __builtin_amdgcn_sched_barrier(0);
    if (rr + 1 < nr && icn != ic) STAGE_W(icn);
    __builtin_amdgcn_sched_barrier(0);
  }
#undef STAGE_X
#undef STAGE_W
}

// ---------------------------------------------------------------------------
// fallback (ws too small): R5 one-pass kernel (proven).
// ---------------------------------------------------------------------------
typedef unsigned int uintv2 __attribute__((ext_vector_type(2)));
#define LD1(cj, i)                                                   \
  ((hok && (w_in0 + (i)) >= 0 && (w_in0 + (i)) < 224)                \
       ? cbase[(size_t)(cj) * 50176 + w_in0 + (i)]                   \
       : 0.f)

__global__ __launch_bounds__(256, 4) void conv_onepass_kernel(
    const float* __restrict__ x, const short* __restrict__ wt,
    const float* __restrict__ bias, float* __restrict__ out) {
  __shared__ short lds[6 * 66 * 32];
  int b0 = blockIdx.x;
  int b = (b0 & 7) * 896 + (b0 >> 3);
  int ht = b % 56;
  int rest = b / 56;
  int w4 = rest & 3, n = rest >> 2;
  int h0 = ht * 4, w0 = w4 * 64;
  int t = threadIdx.x, lane = t & 63, wv = t >> 6;
  int l15 = lane & 15, l4 = lane >> 4;

  facc4 acc[4][4];
#pragma unroll
  for (int om = 0; om < 4; ++om)
#pragma unroll
    for (int p = 0; p < 4; ++p) {
      facc4 z = {0.f, 0.f, 0.f, 0.f};
      acc[om][p] = z;
    }

  for (int ic = 0; ic < 2; ++ic) {
#pragma unroll
    for (int k = 0; k < 4; ++k) {
      int u = t + k * 256;
      if (u < 816) {
        int chg = u & 7;
        int tmp = u >> 3;
        int ccg = tmp % 17, r = tmp / 17;
        int h_in = h0 - 1 + r;
        bool hok = (h_in >= 0) & (h_in < 224);
        int w_in0 = w0 - 1 + ccg * 4;
        int ch0 = ic * 32 + chg * 4;
        const float* cbase =
            x + ((size_t)(n * 64 + ch0) * 224 + (hok ? h_in : 0)) * 224;
        float4 v0, v1, v2, v3;
        if (hok && w_in0 >= 0 && w_in0 + 3 < 224) {
          v0 = *(const float4*)(cbase + w_in0);
          v1 = *(const float4*)(cbase + 50176 + w_in0);
          v2 = *(const float4*)(cbase + 2 * 50176 + w_in0);
          v3 = *(const float4*)(cbase + 3 * 50176 + w_in0);
        } else {
          v0 = make_float4(LD1(0, 0), LD1(0, 1), LD1(0, 2), LD1(0, 3));
          v1 = make_float4(LD1(1, 0), LD1(1, 1), LD1(1, 2), LD1(1, 3));
          v2 = make_float4(LD1(2, 0), LD1(2, 1), LD1(2, 2), LD1(2, 3));
          v3 = make_float4(LD1(3, 0), LD1(3, 1), LD1(3, 2), LD1(3, 3));
        }
        int g = chg >> 1;
        int halfsel = (chg & 1) << 2;
#pragma unroll
        for (int i = 0; i < 4; ++i) {
          int cc = ccg * 4 + i;
          if (cc < 66) {
            float a0 = ((const float*)&v0)[i], a1 = ((const float*)&v1)[i];
            float a2 = ((const float*)&v2)[i], a3 = ((const float*)&v3)[i];
            unsigned int w0p =
                (unsigned int)f2bfu(a0) | ((unsigned int)f2bfu(a1) << 16);
            unsigned int w1p =
                (unsigned int)f2bfu(a2) | ((unsigned int)f2bfu(a3) << 16);
            int addr =
                (r * 66 + cc) * 32 + ((g ^ ((cc >> 1) & 3)) << 3) + halfsel;
            uintv2 pk = {w0p, w1p};
            *(uintv2*)(lds + addr) = pk;
          }
        }
      }
    }
    __syncthreads();
#pragma unroll
    for (int kh = 0; kh < 3; ++kh) {
      int r = wv + kh;
#pragma unroll
      for (int kw = 0; kw < 3; ++kw) {
        const short* wb =
            wt + (((kh * 3 + kw) * 2 + ic) * 64 + l15) * 32 + (l4 << 3);
        bhalf8 a[4];
#pragma unroll
        for (int om = 0; om < 4; ++om)
          a[om] = *(const bhalf8*)(wb + om * 512);
#pragma unroll
        for (int p = 0; p < 4; ++p) {
          int tc = p * 16 + l15 + kw;
          bhalf8 bv = *(const bhalf8*)(lds + (r * 66 + tc) * 32 +
                                       ((l4 ^ ((tc >> 1) & 3)) << 3));
#pragma unroll
          for (int om = 0; om < 4; ++om)
            acc[om][p] = __builtin_amdgcn_mfma_f32_16x16x32_bf16(
                a[om], bv, acc[om][p], 0, 0, 0);
        }
      }
    }
    if (ic == 0) __syncthreads();
  }

  int h = h0 + wv;
#pragma unroll
  for (int om = 0; om < 4; ++om) {
#pragma unroll
    for (int j = 0; j < 4; ++j) {
      int o = om * 16 + l4 * 4 + j;
      float bo = bias[o];
      float* op = out + ((size_t)(n * 64 + o) * 224 + h) * 224 + w0;
#pragma unroll
      for (int p = 0; p < 4; ++p) {
        int wg = w0 + p * 16 + l15;
        if (wg < 224) op[p * 16 + l15] = acc[om][p][j] + bo;
      }
    }
  }
}

extern "C" void kernel_launch(void* const* d_in, const int* in_sizes, int n_in,
                              void* d_out, int out_size, void* d_ws,
                              size_t ws_size, hipStream_t stream) {
  const float* x = (const float*)d_in[0];
  const float* wloc = (const float*)d_in[1];
  const float* wL = (const float*)d_in[2];
  const float* bloc = (const float*)d_in[3];
  const float* bro = (const float*)d_in[4];
  const float* eps_w = (const float*)d_in[5];
  const float* eps_b = (const float*)d_in[6];
  float* outp = (float*)d_out;

  short* wt = (short*)d_ws;                      // 73728 B
  float* bias = (float*)((char*)d_ws + 73728);   // 64 f32
  short* zeros = (short*)((char*)d_ws + 73984);  // 16 bf16 zero pad
  short* xh = (short*)((char*)d_ws + 74240);     // 205.5 MB
  const size_t need = 74240ull + (size_t)32 * 50176 * 64 * 2;

  prep_kernel<<<16, 256, 0, stream>>>(wloc, wL, eps_w, bloc, bro, eps_b, wt,
                                      bias, zeros);
  if (ws_size >= need) {
    to_nhwc_kernel<<<32 * 196, 512, 0, stream>>>(x, xh);
    const int dyn_lds = (21760 + 18432) * 2;  // 80384 B
    hipFuncSetAttribute((const void*)conv_wcloop_kernel,
                        hipFuncAttributeMaxDynamicSharedMemorySize, dyn_lds);
    conv_wcloop_kernel<<<1792, 512, dyn_lds, stream>>>(xh, wt, bias, zeros,
                                                       outp);
  } else {
    conv_onepass_kernel<<<7168, 256, 0, stream>>>(x, wt, bias, outp);
  }
}

// Round 14
// 315.877 us; speedup vs baseline: 1.0796x; 1.0796x over previous
//
#include <hip/hip_runtime.h>
#include <hip/hip_bf16.h>
#include <stdint.h>

typedef short bhalf8 __attribute__((ext_vector_type(8)));
typedef float facc4 __attribute__((ext_vector_type(4)));

static __device__ __forceinline__ unsigned short f2bfu(float f) {
  return __builtin_bit_cast(unsigned short, __float2bfloat16(f));
}

// ---------------------------------------------------------------------------
// prep: sample conv weights w = loc + L@eps (L = tril(-1)+softplus(diag)*I)
// bf16 layout wt[a=kh*3+kw][kc=i>>5][o][i&31], bias, 16-short zero pad.
// ---------------------------------------------------------------------------
__global__ void prep_kernel(const float* __restrict__ wloc,
                            const float* __restrict__ wL,
                            const float* __restrict__ eps_w,
                            const float* __restrict__ bloc,
                            const float* __restrict__ bro,
                            const float* __restrict__ eps_b,
                            short* __restrict__ wt, float* __restrict__ bias,
                            short* __restrict__ zeros) {
  int t = blockIdx.x * 256 + threadIdx.x;  // t = o*64 + i
  int o = t >> 6, i = t & 63;
  int kc = i >> 5, il = i & 31;
  const float* Lp = wL + (size_t)t * 81;
  const float* ep = eps_w + (size_t)t * 9;
  const float* lp = wloc + (size_t)t * 9;
  float e[9];
#pragma unroll
  for (int b = 0; b < 9; ++b) e[b] = ep[b];
#pragma unroll
  for (int a = 0; a < 9; ++a) {
    float s = lp[a];
    for (int b = 0; b < a; ++b) s += Lp[a * 9 + b] * e[b];
    float d = Lp[a * 9 + a];
    float sp = (d > 20.f) ? d : log1pf(expf(d));
    s += sp * e[a];
    wt[((a * 2 + kc) * 64 + o) * 32 + il] = (short)f2bfu(s);
  }
  if (t < 64) {
    float d = bro[t];
    float sp = (d > 20.f) ? d : log1pf(expf(d));
    bias[t] = bloc[t] + eps_b[t] * sp;
  }
  if (t < 16) zeros[t] = 0;
}

// ---------------------------------------------------------------------------
// pass 1: x NCHW f32 -> NHWC bf16 ([n][p=h*224+w][c64]). Streaming ~5.4 TB/s.
// ---------------------------------------------------------------------------
__global__ __launch_bounds__(512) void to_nhwc_kernel(
    const float* __restrict__ x, short* __restrict__ xh) {
  int b = blockIdx.x;
  int n = b / 196;
  int p0 = (b % 196) * 256;
  int t = threadIdx.x;
  int pl = t >> 3, c8 = t & 7;
  const float* xp = x + (size_t)(n * 64 + c8 * 8) * 50176 + p0 + pl * 4;
  short* op = xh + ((size_t)n * 50176 + p0 + pl * 4) * 64 + c8 * 8;
  float4 v[8];
#pragma unroll
  for (int j = 0; j < 8; ++j) v[j] = *(const float4*)(xp + (size_t)j * 50176);
#pragma unroll
  for (int s = 0; s < 4; ++s) {
    bhalf8 h;
#pragma unroll
    for (int j = 0; j < 8; ++j) h[j] = f2bfu(((const float*)&v[j])[s]);
    *(bhalf8*)(op + s * 64) = h;
  }
}

// ---------------------------------------------------------------------------
// pass 2: R12 structure (best so far, ~180us conv) + LDS-bounce epilogue.
// Block = 8 waves, 64o x 8r x 32px, 2 ic rounds, x dbuf + wt single, counted
// vmcnt, setprio. NEW: epilogue bounces acc through per-wave padded LDS
// slices so every global store is a full 128-B segment (R6's exact-401MB
// write behavior) instead of 4x64-B segments (R11/R12's +78MB RMW traffic).
// Grid 6272 = 28ht x 7wc x 32n, vertical-adjacent consecutive + XCD chunk.
// ---------------------------------------------------------------------------
#define XBUF 10880  // shorts per x buffer (1360 chunks * 8)

__global__ __launch_bounds__(512, 4) void conv_x32_kernel(
    const short* __restrict__ xh, const short* __restrict__ wtg,
    const float* __restrict__ bias, const short* __restrict__ zeros,
    float* __restrict__ out) {
  extern __shared__ short smem[];
  short* lds_x = smem;           // 2 * 10880 shorts = 43520 B
  short* lds_w = smem + 21760;   // 2304 chunks * 8 = 18432 shorts = 36864 B

  int b0 = blockIdx.x;
  int b = (b0 & 7) * 784 + (b0 >> 3);  // bijective: 6272 % 8 == 0
  int ht = b % 28;
  int rest = b / 28;
  int wc = rest % 7, n = rest / 7;
  int h0 = ht * 8, w0 = wc * 32;
  int t = threadIdx.x, lane = t & 63, wv = t >> 6;
  int l15 = lane & 15, l4 = lane >> 4;
  const size_t nbase = (size_t)n * 50176 * 64;

  // ---- round-invariant x source offsets: 1360 chunks, id=(r*4+g)*34+cc ----
  int pre_px[3];
#pragma unroll
  for (int k = 0; k < 3; ++k) {
    int id = k * 512 + t;
    int idc = (id < 1360) ? id : 0;
    int cc = idc % 34;
    int rg = idc / 34;
    int g = rg & 3, r = rg >> 2;
    int h_in = h0 - 1 + r, w_in = w0 - 1 + cc;
    bool ok = (h_in >= 0) & (h_in < 224) & (w_in >= 0) & (w_in < 224);
    pre_px[k] = ok ? ((h_in * 224 + w_in) * 64 + g * 8) : -1;
  }

#define STAGE_X(bufsel, ic_)                                               \
  do {                                                                     \
    const short* gx_ = xh + nbase + (ic_)*32;                              \
    short* lx_ = lds_x + (bufsel)*XBUF;                                    \
    _Pragma("unroll") for (int k = 0; k < 3; ++k) {                        \
      if (k * 512 + t < 1360) {                                            \
        const short* src = (pre_px[k] >= 0) ? gx_ + pre_px[k] : zeros;     \
        __builtin_amdgcn_global_load_lds(                                  \
            (const __attribute__((address_space(1))) void*)src,            \
            (__attribute__((address_space(3))) void*)(lx_ +                \
                                                      (k * 512 + wv * 64) * \
                                                          8),              \
            16, 0, 0);                                                     \
      }                                                                    \
    }                                                                      \
  } while (0)

  // wt: 2304 chunks, id = a*256 + g*64 + o; LDS [9a][4g][64o][8ch]
#define STAGE_W(ic_)                                                       \
  do {                                                                     \
    _Pragma("unroll") for (int k = 0; k < 5; ++k) {                        \
      int id = k * 512 + t;                                                \
      if (id < 2304) {                                                     \
        int a_ = id >> 8, rem_ = id & 255;                                 \
        int g_ = rem_ >> 6, o_ = rem_ & 63;                                \
        const short* src =                                                 \
            wtg + ((a_ * 2 + (ic_)) * 64 + o_) * 32 + g_ * 8;              \
        __builtin_amdgcn_global_load_lds(                                  \
            (const __attribute__((address_space(1))) void*)src,            \
            (__attribute__((address_space(3))) void*)(lds_w +              \
                                                      (k * 512 + wv * 64) * \
                                                          8),              \
            16, 0, 0);                                                     \
      }                                                                    \
    }                                                                      \
  } while (0)

  facc4 acc[4][2];
#pragma unroll
  for (int om = 0; om < 4; ++om)
#pragma unroll
    for (int p = 0; p < 2; ++p) {
      facc4 z = {0.f, 0.f, 0.f, 0.f};
      acc[om][p] = z;
    }

#define COMPUTE(bufsel)                                                    \
  do {                                                                     \
    const short* bx = lds_x + (bufsel)*XBUF;                               \
    __builtin_amdgcn_s_setprio(1);                                         \
    _Pragma("unroll") for (int kh = 0; kh < 3; ++kh) {                     \
      int r = wv + kh;                                                     \
      _Pragma("unroll") for (int kw = 0; kw < 3; ++kw) {                   \
        const int a_ = kh * 3 + kw;                                        \
        bhalf8 av[4];                                                      \
        _Pragma("unroll") for (int om = 0; om < 4; ++om) av[om] =          \
            *(const bhalf8*)(lds_w +                                       \
                             ((a_ * 4 + l4) * 64 + om * 16 + l15) * 8);    \
        _Pragma("unroll") for (int p = 0; p < 2; ++p) {                    \
          int tc = p * 16 + l15 + kw;                                      \
          bhalf8 bv =                                                      \
              *(const bhalf8*)(bx + ((r * 4 + l4) * 34 + tc) * 8);         \
          _Pragma("unroll") for (int om = 0; om < 4; ++om) acc[om][p] =    \
              __builtin_amdgcn_mfma_f32_16x16x32_bf16(av[om], bv,          \
                                                      acc[om][p], 0, 0,    \
                                                      0);                  \
        }                                                                  \
      }                                                                    \
    }                                                                      \
    __builtin_amdgcn_s_setprio(0);                                         \
  } while (0)

  // ---- schedule (R12-proven) ----
  STAGE_X(0, 0);
  STAGE_W(0);
  asm volatile("s_waitcnt vmcnt(0)" ::: "memory");
  __builtin_amdgcn_sched_barrier(0);
  __builtin_amdgcn_s_barrier();
  __builtin_amdgcn_sched_barrier(0);

  STAGE_X(1, 1);  // prefetch round-2 x into idle buffer (hidden)
  __builtin_amdgcn_sched_barrier(0);
  COMPUTE(0);
  __builtin_amdgcn_s_barrier();  // all wt reads of round 0 done
  __builtin_amdgcn_sched_barrier(0);
  STAGE_W(1);                    // overwrite wt buffer
  asm volatile("s_waitcnt vmcnt(0)" ::: "memory");  // x(1) landed + wt(1)
  __builtin_amdgcn_sched_barrier(0);
  __builtin_amdgcn_s_barrier();
  __builtin_amdgcn_sched_barrier(0);
  COMPUTE(1);

#undef STAGE_X
#undef STAGE_W
#undef COMPUTE

  // ---- epilogue via LDS bounce: full-128B global write segments ----
  __builtin_amdgcn_s_barrier();  // all x/wt LDS reads done -> reuse LDS
  __builtin_amdgcn_sched_barrier(0);
  // per-wave slice: 64o x 32px f32, row stride 33 (pad) = 8448 B; 8*8448 =
  // 67.6 KB <= 80.4 KB allocated.
  float* lbo = (float*)smem + wv * 2112;
#pragma unroll
  for (int om = 0; om < 4; ++om)
#pragma unroll
    for (int p = 0; p < 2; ++p)
#pragma unroll
      for (int jj = 0; jj < 4; ++jj)
        lbo[(om * 16 + l4 * 4 + jj) * 33 + p * 16 + l15] = acc[om][p][jj];
  // wave-private slice: own-wave ds visibility only (compiler waits lgkm)
  int h = h0 + wv;
  int og = lane >> 3, pxg = lane & 7;
#pragma unroll
  for (int s = 0; s < 8; ++s) {
    int o = s * 8 + og;
    float bo = bias[o];
    float4 v = *(const float4*)(lbo + o * 33 + pxg * 4);
    float4 rv = make_float4(v.x + bo, v.y + bo, v.z + bo, v.w + bo);
    // lanes 0..7 (og fixed? no: og = lane>>3) -> per og-group 8 lanes cover
    // 32 consecutive px = 128 B: every store segment is a full line.
    *(float4*)(out + ((size_t)(n * 64 + o) * 224 + h) * 224 + w0 + pxg * 4) =
        rv;
  }
}

// ---------------------------------------------------------------------------
// fallback (ws too small): R5 one-pass kernel (proven).
// ---------------------------------------------------------------------------
typedef unsigned int uintv2 __attribute__((ext_vector_type(2)));
#define LD1(cj, i)                                                   \
  ((hok && (w_in0 + (i)) >= 0 && (w_in0 + (i)) < 224)                \
       ? cbase[(size_t)(cj) * 50176 + w_in0 + (i)]                   \
       : 0.f)

__global__ __launch_bounds__(256, 4) void conv_onepass_kernel(
    const float* __restrict__ x, const short* __restrict__ wt,
    const float* __restrict__ bias, float* __restrict__ out) {
  __shared__ short lds[6 * 66 * 32];
  int b0 = blockIdx.x;
  int b = (b0 & 7) * 896 + (b0 >> 3);
  int ht = b % 56;
  int rest = b / 56;
  int w4 = rest & 3, n = rest >> 2;
  int h0 = ht * 4, w0 = w4 * 64;
  int t = threadIdx.x, lane = t & 63, wv = t >> 6;
  int l15 = lane & 15, l4 = lane >> 4;

  facc4 acc[4][4];
#pragma unroll
  for (int om = 0; om < 4; ++om)
#pragma unroll
    for (int p = 0; p < 4; ++p) {
      facc4 z = {0.f, 0.f, 0.f, 0.f};
      acc[om][p] = z;
    }

  for (int ic = 0; ic < 2; ++ic) {
#pragma unroll
    for (int k = 0; k < 4; ++k) {
      int u = t + k * 256;
      if (u < 816) {
        int chg = u & 7;
        int tmp = u >> 3;
        int ccg = tmp % 17, r = tmp / 17;
        int h_in = h0 - 1 + r;
        bool hok = (h_in >= 0) & (h_in < 224);
        int w_in0 = w0 - 1 + ccg * 4;
        int ch0 = ic * 32 + chg * 4;
        const float* cbase =
            x + ((size_t)(n * 64 + ch0) * 224 + (hok ? h_in : 0)) * 224;
        float4 v0, v1, v2, v3;
        if (hok && w_in0 >= 0 && w_in0 + 3 < 224) {
          v0 = *(const float4*)(cbase + w_in0);
          v1 = *(const float4*)(cbase + 50176 + w_in0);
          v2 = *(const float4*)(cbase + 2 * 50176 + w_in0);
          v3 = *(const float4*)(cbase + 3 * 50176 + w_in0);
        } else {
          v0 = make_float4(LD1(0, 0), LD1(0, 1), LD1(0, 2), LD1(0, 3));
          v1 = make_float4(LD1(1, 0), LD1(1, 1), LD1(1, 2), LD1(1, 3));
          v2 = make_float4(LD1(2, 0), LD1(2, 1), LD1(2, 2), LD1(2, 3));
          v3 = make_float4(LD1(3, 0), LD1(3, 1), LD1(3, 2), LD1(3, 3));
        }
        int g = chg >> 1;
        int halfsel = (chg & 1) << 2;
#pragma unroll
        for (int i = 0; i < 4; ++i) {
          int cc = ccg * 4 + i;
          if (cc < 66) {
            float a0 = ((const float*)&v0)[i], a1 = ((const float*)&v1)[i];
            float a2 = ((const float*)&v2)[i], a3 = ((const float*)&v3)[i];
            unsigned int w0p =
                (unsigned int)f2bfu(a0) | ((unsigned int)f2bfu(a1) << 16);
            unsigned int w1p =
                (unsigned int)f2bfu(a2) | ((unsigned int)f2bfu(a3) << 16);
            int addr =
                (r * 66 + cc) * 32 + ((g ^ ((cc >> 1) & 3)) << 3) + halfsel;
            uintv2 pk = {w0p, w1p};
            *(uintv2*)(lds + addr) = pk;
          }
        }
      }
    }
    __syncthreads();
#pragma unroll
    for (int kh = 0; kh < 3; ++kh) {
      int r = wv + kh;
#pragma unroll
      for (int kw = 0; kw < 3; ++kw) {
        const short* wb =
            wt + (((kh * 3 + kw) * 2 + ic) * 64 + l15) * 32 + (l4 << 3);
        bhalf8 a[4];
#pragma unroll
        for (int om = 0; om < 4; ++om)
          a[om] = *(const bhalf8*)(wb + om * 512);
#pragma unroll
        for (int p = 0; p < 4; ++p) {
          int tc = p * 16 + l15 + kw;
          bhalf8 bv = *(const bhalf8*)(lds + (r * 66 + tc) * 32 +
                                       ((l4 ^ ((tc >> 1) & 3)) << 3));
#pragma unroll
          for (int om = 0; om < 4; ++om)
            acc[om][p] = __builtin_amdgcn_mfma_f32_16x16x32_bf16(
                a[om], bv, acc[om][p], 0, 0, 0);
        }
      }
    }
    if (ic == 0) __syncthreads();
  }

  int h = h0 + wv;
#pragma unroll
  for (int om = 0; om < 4; ++om) {
#pragma unroll
    for (int j = 0; j < 4; ++j) {
      int o = om * 16 + l4 * 4 + j;
      float bo = bias[o];
      float* op = out + ((size_t)(n * 64 + o) * 224 + h) * 224 + w0;
#pragma unroll
      for (int p = 0; p < 4; ++p) {
        int wg = w0 + p * 16 + l15;
        if (wg < 224) op[p * 16 + l15] = acc[om][p][j] + bo;
      }
    }
  }
}

extern "C" void kernel_launch(void* const* d_in, const int* in_sizes, int n_in,
                              void* d_out, int out_size, void* d_ws,
                              size_t ws_size, hipStream_t stream) {
  const float* x = (const float*)d_in[0];
  const float* wloc = (const float*)d_in[1];
  const float* wL = (const float*)d_in[2];
  const float* bloc = (const float*)d_in[3];
  const float* bro = (const float*)d_in[4];
  const float* eps_w = (const float*)d_in[5];
  const float* eps_b = (const float*)d_in[6];
  float* outp = (float*)d_out;

  short* wt = (short*)d_ws;                      // 73728 B
  float* bias = (float*)((char*)d_ws + 73728);   // 64 f32
  short* zeros = (short*)((char*)d_ws + 73984);  // 16 bf16 zero pad
  short* xh = (short*)((char*)d_ws + 74240);     // 205.5 MB
  const size_t need = 74240ull + (size_t)32 * 50176 * 64 * 2;

  prep_kernel<<<16, 256, 0, stream>>>(wloc, wL, eps_w, bloc, bro, eps_b, wt,
                                      bias, zeros);
  if (ws_size >= need) {
    to_nhwc_kernel<<<32 * 196, 512, 0, stream>>>(x, xh);
    const int dyn_lds = (21760 + 18432) * 2;  // 80384 B
    hipFuncSetAttribute((const void*)conv_x32_kernel,
                        hipFuncAttributeMaxDynamicSharedMemorySize, dyn_lds);
    conv_x32_kernel<<<6272, 512, dyn_lds, stream>>>(xh, wt, bias, zeros, outp);
  } else {
    conv_onepass_kernel<<<7168, 256, 0, stream>>>(x, wt, bias, outp);
  }
}

// Round 15
// 279.019 us; speedup vs baseline: 1.2222x; 1.1321x over previous
//
#include <hip/hip_runtime.h>
#include <hip/hip_bf16.h>
#include <stdint.h>

typedef short bhalf8 __attribute__((ext_vector_type(8)));
typedef float facc4 __attribute__((ext_vector_type(4)));
typedef unsigned int uintv2 __attribute__((ext_vector_type(2)));

static __device__ __forceinline__ unsigned short f2bfu(float f) {
  return __builtin_bit_cast(unsigned short, __float2bfloat16(f));
}

// ---------------------------------------------------------------------------
// prep: sample conv weights w = loc + L@eps (L = tril(-1)+softplus(diag)*I)
// bf16 layout wt[a=kh*3+kw][kc=i>>5][o][i&31] (R12-proven), bias.
// ---------------------------------------------------------------------------
__global__ void prep_kernel(const float* __restrict__ wloc,
                            const float* __restrict__ wL,
                            const float* __restrict__ eps_w,
                            const float* __restrict__ bloc,
                            const float* __restrict__ bro,
                            const float* __restrict__ eps_b,
                            short* __restrict__ wt, float* __restrict__ bias) {
  int t = blockIdx.x * 256 + threadIdx.x;  // t = o*64 + i
  int o = t >> 6, i = t & 63;
  int kc = i >> 5, il = i & 31;
  const float* Lp = wL + (size_t)t * 81;
  const float* ep = eps_w + (size_t)t * 9;
  const float* lp = wloc + (size_t)t * 9;
  float e[9];
#pragma unroll
  for (int b = 0; b < 9; ++b) e[b] = ep[b];
#pragma unroll
  for (int a = 0; a < 9; ++a) {
    float s = lp[a];
    for (int b = 0; b < a; ++b) s += Lp[a * 9 + b] * e[b];
    float d = Lp[a * 9 + a];
    float sp = (d > 20.f) ? d : log1pf(expf(d));
    s += sp * e[a];
    wt[((a * 2 + kc) * 64 + o) * 32 + il] = (short)f2bfu(s);
  }
  if (t < 64) {
    float d = bro[t];
    float sp = (d > 20.f) ? d : log1pf(expf(d));
    bias[t] = bloc[t] + eps_b[t] * sp;
  }
}

// ---------------------------------------------------------------------------
// fused one-pass conv on the R12 skeleton. Block = 8 waves, 64o x 8r x 32px,
// 2 ic rounds. x staged from NCHW f32 via register transpose (R5-proven
// math): 720 units of 4px x 4ch, float4 loads, hw bf16 cvt, ds_write_b64
// into R12's LDS layout [10r][4g][34cc][8ch] (dbuf, 2x21.76 KB). wt DMA'd
// to LDS [9a][4g][64o][8ch] (36.9 KB, restaged per ic). 80.4 KB -> 2
// blocks/CU. T14: round-1 global loads ISSUE before round-0 MFMA (HBM
// latency hides under ~720 cyc compute); cvt+ds_write after the reads-done
// barrier. No to_nhwc pass, no xh workspace: x traffic 888 -> ~580 MB.
// Grid 6272 = 28ht x 7wc x 32n, vertical-adjacent + XCD chunk (halo L2).
// ---------------------------------------------------------------------------
#define XBUF 10880  // shorts per x buffer (1360 chunks * 8)

#define LD1(cj, i)                                                    \
  ((hok && (w_in0 + (i)) >= 0 && (w_in0 + (i)) < 224)                 \
       ? cbase[(size_t)(cj)*50176 + w_in0 + (i)]                      \
       : 0.f)

__global__ __launch_bounds__(512, 4) void conv_fused_kernel(
    const float* __restrict__ x, const short* __restrict__ wtg,
    const float* __restrict__ bias, float* __restrict__ out) {
  extern __shared__ short smem[];
  short* lds_x = smem;          // 2 * 10880 shorts = 43520 B
  short* lds_w = smem + 21760;  // 2304 chunks * 8 = 18432 shorts = 36864 B

  int b0 = blockIdx.x;
  int b = (b0 & 7) * 784 + (b0 >> 3);  // bijective: 6272 % 8 == 0
  int ht = b % 28;
  int rest = b / 28;
  int wc = rest % 7, n = rest / 7;
  int h0 = ht * 8, w0 = wc * 32;
  int t = threadIdx.x, lane = t & 63, wv = t >> 6;
  int l15 = lane & 15, l4 = lane >> 4;

  // ---- x staging: load 4px x 4ch f32 into regs (units u = t + k*512) ----
#define LOADX(V, ic_)                                                       \
  do {                                                                      \
    _Pragma("unroll") for (int k = 0; k < 2; ++k) {                         \
      int u = t + k * 512;                                                  \
      if (u < 720) {                                                        \
        int chg = u & 7, tmp = u >> 3;                                      \
        int ccg = tmp % 9, r = tmp / 9;                                     \
        int h_in = h0 - 1 + r;                                              \
        bool hok = (h_in >= 0) & (h_in < 224);                              \
        int w_in0 = w0 - 1 + ccg * 4;                                       \
        const float* cbase =                                                \
            x + ((size_t)(n * 64 + (ic_)*32 + chg * 4) * 224 +              \
                 (hok ? h_in : 0)) *                                        \
                    224;                                                    \
        if (hok && w_in0 >= 0 && w_in0 + 3 < 224) {                         \
          V[k][0] = *(const float4*)(cbase + w_in0);                        \
          V[k][1] = *(const float4*)(cbase + 50176 + w_in0);                \
          V[k][2] = *(const float4*)(cbase + 2 * 50176 + w_in0);            \
          V[k][3] = *(const float4*)(cbase + 3 * 50176 + w_in0);            \
        } else {                                                            \
          V[k][0] = make_float4(LD1(0, 0), LD1(0, 1), LD1(0, 2), LD1(0, 3)); \
          V[k][1] = make_float4(LD1(1, 0), LD1(1, 1), LD1(1, 2), LD1(1, 3)); \
          V[k][2] = make_float4(LD1(2, 0), LD1(2, 1), LD1(2, 2), LD1(2, 3)); \
          V[k][3] = make_float4(LD1(3, 0), LD1(3, 1), LD1(3, 2), LD1(3, 3)); \
        }                                                                   \
      }                                                                     \
    }                                                                       \
  } while (0)

  // ---- cvt + pack + ds_write into [10r][4g][34cc][8ch] (no swizzle) ----
#define CVTW(bufsel, V)                                                     \
  do {                                                                      \
    short* lx_ = lds_x + (bufsel)*XBUF;                                     \
    _Pragma("unroll") for (int k = 0; k < 2; ++k) {                         \
      int u = t + k * 512;                                                  \
      if (u < 720) {                                                        \
        int chg = u & 7, tmp = u >> 3;                                      \
        int ccg = tmp % 9, r = tmp / 9;                                     \
        int g = chg >> 1, hs = (chg & 1) << 2;                              \
        _Pragma("unroll") for (int i = 0; i < 4; ++i) {                     \
          int cc = ccg * 4 + i;                                             \
          if (cc < 34) {                                                    \
            float a0 = ((const float*)&V[k][0])[i];                         \
            float a1 = ((const float*)&V[k][1])[i];                         \
            float a2 = ((const float*)&V[k][2])[i];                         \
            float a3 = ((const float*)&V[k][3])[i];                         \
            unsigned int p0 =                                               \
                (unsigned int)f2bfu(a0) | ((unsigned int)f2bfu(a1) << 16);  \
            unsigned int p1 =                                               \
                (unsigned int)f2bfu(a2) | ((unsigned int)f2bfu(a3) << 16);  \
            uintv2 pk = {p0, p1};                                           \
            *(uintv2*)(lx_ + (((r * 4 + g) * 34 + cc) << 3) + hs) = pk;     \
          }                                                                 \
        }                                                                   \
      }                                                                     \
    }                                                                       \
  } while (0)

  // ---- wt DMA: 2304 chunks, id = a*256 + g*64 + o (R12-proven) ----
#define STAGE_W(ic_)                                                        \
  do {                                                                      \
    _Pragma("unroll") for (int k = 0; k < 5; ++k) {                         \
      int id = k * 512 + t;                                                 \
      if (id < 2304) {                                                      \
        int a_ = id >> 8, rem_ = id & 255;                                  \
        int g_ = rem_ >> 6, o_ = rem_ & 63;                                 \
        const short* src =                                                  \
            wtg + ((a_ * 2 + (ic_)) * 64 + o_) * 32 + g_ * 8;               \
        __builtin_amdgcn_global_load_lds(                                   \
            (const __attribute__((address_space(1))) void*)src,             \
            (__attribute__((address_space(3))) void*)(lds_w +               \
                                                      (k * 512 + wv * 64) * \
                                                          8),               \
            16, 0, 0);                                                      \
      }                                                                     \
    }                                                                       \
  } while (0)

  facc4 acc[4][2];
#pragma unroll
  for (int om = 0; om < 4; ++om)
#pragma unroll
    for (int p = 0; p < 2; ++p) {
      facc4 z = {0.f, 0.f, 0.f, 0.f};
      acc[om][p] = z;
    }

#define COMPUTE(bufsel)                                                     \
  do {                                                                      \
    const short* bx = lds_x + (bufsel)*XBUF;                                \
    __builtin_amdgcn_s_setprio(1);                                          \
    _Pragma("unroll") for (int kh = 0; kh < 3; ++kh) {                      \
      int r = wv + kh;                                                      \
      _Pragma("unroll") for (int kw = 0; kw < 3; ++kw) {                    \
        const int a_ = kh * 3 + kw;                                         \
        bhalf8 av[4];                                                       \
        _Pragma("unroll") for (int om = 0; om < 4; ++om) av[om] =           \
            *(const bhalf8*)(lds_w +                                        \
                             ((a_ * 4 + l4) * 64 + om * 16 + l15) * 8);     \
        _Pragma("unroll") for (int p = 0; p < 2; ++p) {                     \
          int tc = p * 16 + l15 + kw;                                       \
          bhalf8 bv = *(const bhalf8*)(bx + ((r * 4 + l4) * 34 + tc) * 8);  \
          _Pragma("unroll") for (int om = 0; om < 4; ++om) acc[om][p] =     \
              __builtin_amdgcn_mfma_f32_16x16x32_bf16(av[om], bv,           \
                                                      acc[om][p], 0, 0, 0); \
        }                                                                   \
      }                                                                     \
    }                                                                       \
    __builtin_amdgcn_s_setprio(0);                                          \
  } while (0)

  float4 xv[2][4];

  // ---- prologue: stage wt(ic0) + x(ic0) ----
  STAGE_W(0);
  LOADX(xv, 0);
  CVTW(0, xv);
  asm volatile("s_waitcnt vmcnt(0)" ::: "memory");  // wt DMA landed
  __syncthreads();                                  // ds_writes visible

  // ---- round 0: issue round-1 x loads EARLY (hide under MFMA) ----
  LOADX(xv, 1);
  __builtin_amdgcn_sched_barrier(0);
  COMPUTE(0);
  __builtin_amdgcn_s_barrier();  // all reads of buf0 + wt(ic0) done
  __builtin_amdgcn_sched_barrier(0);
  STAGE_W(1);
  CVTW(1, xv);  // xv landed during COMPUTE(0)
  asm volatile("s_waitcnt vmcnt(0)" ::: "memory");  // wt(ic1) landed
  __syncthreads();
  COMPUTE(1);

#undef LOADX
#undef CVTW
#undef STAGE_W
#undef COMPUTE

  // ---- epilogue: R12 direct stores (R14 bounce reverted) ----
  int h = h0 + wv;
#pragma unroll
  for (int om = 0; om < 4; ++om) {
#pragma unroll
    for (int jj = 0; jj < 4; ++jj) {
      int o = om * 16 + l4 * 4 + jj;
      float bo = bias[o];
      float* op = out + ((size_t)(n * 64 + o) * 224 + h) * 224 + w0;
#pragma unroll
      for (int p = 0; p < 2; ++p) op[p * 16 + l15] = acc[om][p][jj] + bo;
    }
  }
}

extern "C" void kernel_launch(void* const* d_in, const int* in_sizes, int n_in,
                              void* d_out, int out_size, void* d_ws,
                              size_t ws_size, hipStream_t stream) {
  const float* x = (const float*)d_in[0];
  const float* wloc = (const float*)d_in[1];
  const float* wL = (const float*)d_in[2];
  const float* bloc = (const float*)d_in[3];
  const float* bro = (const float*)d_in[4];
  const float* eps_w = (const float*)d_in[5];
  const float* eps_b = (const float*)d_in[6];
  float* outp = (float*)d_out;

  short* wt = (short*)d_ws;                     // 73728 B
  float* bias = (float*)((char*)d_ws + 73728);  // 64 f32

  prep_kernel<<<16, 256, 0, stream>>>(wloc, wL, eps_w, bloc, bro, eps_b, wt,
                                      bias);
  const int dyn_lds = (21760 + 18432) * 2;  // 80384 B
  hipFuncSetAttribute((const void*)conv_fused_kernel,
                      hipFuncAttributeMaxDynamicSharedMemorySize, dyn_lds);
  conv_fused_kernel<<<6272, 512, dyn_lds, stream>>>(x, wt, bias, outp);
}